// Round 5
// baseline (153.079 us; speedup 1.0000x reference)
//
#include <hip/hip_runtime.h>

#define NLEV 8
#define PTS_PER_BLOCK 32
#define ROW_F 51   // 3 + 6*NLEV

// ---------------------------------------------------------------------------
// Phase repack: data (T anchors x 3 f32) -> tab (T x 16B entries).
// Entry i = z-pair {anchor i, anchor i+1} as 6 x u16 phases (revolutions/65536),
// phase = fract(val * 2^l / 2pi), l = level owning anchor i.
// Valid pair bases never cross a z-column/level boundary, so using level(i)'s
// frequency for the neighbor is correct wherever the entry is legally read.
// ---------------------------------------------------------------------------
__global__ __launch_bounds__(256) void phase_repack(
    const float* __restrict__ data,
    const int*   __restrict__ level_offsets,
    uint4* __restrict__ tab, int T)
{
    __shared__ float sv[(256 + 1) * 3];
    __shared__ int   soff[NLEV];
    const int tid  = threadIdx.x;
    const int base = blockIdx.x * 256;

    if (tid < NLEV) soff[tid] = level_offsets[tid];
    for (int k = tid; k < (256 + 1) * 3; k += 256) {
        const int gi = base * 3 + k;
        sv[k] = (gi < T * 3) ? data[gi] : 0.0f;   // coalesced stream
    }
    __syncthreads();

    const int i = base + tid;
    if (i >= T) return;

    int l = 0;
    #pragma unroll
    for (int j = 1; j < NLEV; ++j) l += (i >= soff[j]) ? 1 : 0;
    const float s = exp2f((float)l) * 0.15915494309189535f;   // freq / 2pi

    unsigned q[6];
    #pragma unroll
    for (int k = 0; k < 6; ++k) {                 // k<3: anchor i, k>=3: anchor i+1
        float f = sv[tid * 3 + k] * s;
        f -= floorf(f);                           // [0,1) revolutions
        const unsigned v = (unsigned)(f * 65536.0f + 0.5f);
        q[k] = v & 0xffffu;                       // 65536 wraps to 0 (periodic: OK)
    }
    tab[i] = make_uint4(q[0] | (q[1] << 16), q[2], q[3] | (q[4] << 16), q[5]);
}

// sin/cos on revolutions in [0,1): pre-reduced domain per gfx950 ISA
__device__ __forceinline__ void sincos_rev(float r, float& sn, float& cs) {
    asm volatile("v_sin_f32 %0, %1" : "=v"(sn) : "v"(r));
    asm volatile("v_cos_f32 %0, %1" : "=v"(cs) : "v"(r));
}

// ---------------------------------------------------------------------------
// Main kernel: gather = 4 aligned dwordx4 per (point,level) unit.
// ---------------------------------------------------------------------------
__global__ __launch_bounds__(256) void dagrid_kernel(
    const float* __restrict__ xyz,
    const uint4* __restrict__ tab,
    const float* __restrict__ scales,
    const int*   __restrict__ level_offsets,
    const float* __restrict__ bounds,
    float* __restrict__ out,
    int npts)
{
    __shared__ alignas(16) float sxyz[PTS_PER_BLOCK * 3];
    __shared__ alignas(16) float sres[PTS_PER_BLOCK][ROW_F];

    const int tid = threadIdx.x;
    const int l   = tid & 7;        // level
    const int p   = tid >> 3;       // local point 0..31
    const int block_base = blockIdx.x * PTS_PER_BLOCK;
    const bool full_block = (block_base + PTS_PER_BLOCK <= npts);

    if (full_block) {
        if (tid < 24)
            ((float4*)sxyz)[tid] = ((const float4*)(xyz + (size_t)block_base * 3))[tid];
    } else if (tid < PTS_PER_BLOCK * 3) {
        const int gi = block_base * 3 + tid;
        sxyz[tid] = (gi < npts * 3) ? xyz[gi] : 0.0f;
    }

    const float scale = scales[l];
    const int   off_l = level_offsets[l];

    const float lox = bounds[0], loy = bounds[1], loz = bounds[2];
    const float hix = bounds[3] - 1e-6f;
    const float hiy = bounds[4] - 1e-6f;
    const float hiz = bounds[5] - 1e-6f;
    const float size = fmaxf(fmaxf(bounds[3] - bounds[0], bounds[4] - bounds[1]),
                             bounds[5] - bounds[2]);
    const float inv_size = 1.0f / size;

    __syncthreads();

    const int n = block_base + p;
    const bool active = (n < npts);

    const float rx = sxyz[p * 3 + 0];
    const float ry = sxyz[p * 3 + 1];
    const float rz = sxyz[p * 3 + 2];

    float acc0 = 0.f, acc1 = 0.f, acc2 = 0.f, acc3 = 0.f, acc4 = 0.f, acc5 = 0.f;

    if (active) {
        const float x = fminf(fmaxf(rx, lox), hix);
        const float y = fminf(fmaxf(ry, loy), hiy);
        const float z = fminf(fmaxf(rz, loz), hiz);
        const float xn = (x - lox) * inv_size;
        const float yn = (y - loy) * inv_size;
        const float zn = (z - loz) * inv_size;

        const int r1   = (int)scale + 1;
        const int r1sq = r1 * r1;

        const float fx = xn * scale;
        const float fy = yn * scale;
        const float fz = zn * scale;
        const float bxf = floorf(fx), byf = floorf(fy), bzf = floorf(fz);
        const float ox = fx - bxf;
        const float oy = fy - byf;
        const float oz = fz - bzf;

        const int i000 = (int)bxf * r1sq + (int)byf * r1 + (int)bzf + off_l;

        // ---- gather: 4 corner-pairs, ONE aligned dwordx4 each (16 dwords total)
        const uint4 e0 = tab[i000];
        const uint4 e1 = tab[i000 + r1];
        const uint4 e2 = tab[i000 + r1sq];
        const uint4 e3 = tab[i000 + r1sq + r1];

        const float wz0 = 1.0f - oz;
        const float wx1 = ox, wx0 = 1.0f - ox;
        const float wy1 = oy, wy0 = 1.0f - oy;
        const float K = 1.0f / 65536.0f;   // u16 phase -> revolutions

        float sn, cs;
        // e = [p0x|p0y<<16, p0z, p1x|p1y<<16, p1z]; corner (..,0) weight w0, (..,1) w1
        #define PAIRE(e, WXY)                                                        \
        {                                                                            \
            const float w0 = (WXY) * wz0;                                            \
            const float w1 = (WXY) * oz;                                             \
            sincos_rev((float)(e.x & 0xffffu) * K, sn, cs); acc0 += w0*sn; acc3 += w0*cs; \
            sincos_rev((float)(e.x >> 16)     * K, sn, cs); acc1 += w0*sn; acc4 += w0*cs; \
            sincos_rev((float)(e.y & 0xffffu) * K, sn, cs); acc2 += w0*sn; acc5 += w0*cs; \
            sincos_rev((float)(e.z & 0xffffu) * K, sn, cs); acc0 += w1*sn; acc3 += w1*cs; \
            sincos_rev((float)(e.z >> 16)     * K, sn, cs); acc1 += w1*sn; acc4 += w1*cs; \
            sincos_rev((float)(e.w & 0xffffu) * K, sn, cs); acc2 += w1*sn; acc5 += w1*cs; \
        }
        PAIRE(e0, wx0 * wy0)
        PAIRE(e1, wx0 * wy1)
        PAIRE(e2, wx1 * wy0)
        PAIRE(e3, wx1 * wy1)
        #undef PAIRE
    }

    {
        float* row = sres[p];
        const int c = 3 + l * 6;
        row[c + 0] = acc0; row[c + 1] = acc1; row[c + 2] = acc2;
        row[c + 3] = acc3; row[c + 4] = acc4; row[c + 5] = acc5;
        if (l == 0) { row[0] = rx; row[1] = ry; row[2] = rz; }
    }
    __syncthreads();

    if (full_block) {
        const float4* flat4 = (const float4*)&sres[0][0];
        float4* ob4 = (float4*)(out + (size_t)block_base * ROW_F);
        for (int i = tid; i < (PTS_PER_BLOCK * ROW_F) / 4; i += 256)
            ob4[i] = flat4[i];
    } else {
        const float* flat = &sres[0][0];
        float* ob = out + (size_t)block_base * ROW_F;
        const int lim = npts * ROW_F - block_base * ROW_F;
        for (int i = tid; i < PTS_PER_BLOCK * ROW_F; i += 256)
            if (i < lim) ob[i] = flat[i];
    }
}

// ---------------------------------------------------------------------------
// Fallback (ws too small): R3 direct fp32 gather (x4u + x2u), known-good.
// ---------------------------------------------------------------------------
typedef float f4u __attribute__((ext_vector_type(4), aligned(4)));
typedef float f2u __attribute__((ext_vector_type(2), aligned(4)));

__global__ __launch_bounds__(256) void dagrid_kernel_direct(
    const float* __restrict__ xyz,
    const float* __restrict__ data,
    const float* __restrict__ scales,
    const int*   __restrict__ level_offsets,
    const float* __restrict__ bounds,
    float* __restrict__ out,
    int npts)
{
    __shared__ alignas(16) float sxyz[PTS_PER_BLOCK * 3];
    __shared__ alignas(16) float sres[PTS_PER_BLOCK][ROW_F];

    const int tid = threadIdx.x;
    const int l   = tid & 7;
    const int p   = tid >> 3;
    const int block_base = blockIdx.x * PTS_PER_BLOCK;

    if (tid < PTS_PER_BLOCK * 3) {
        const int gi = block_base * 3 + tid;
        sxyz[tid] = (gi < npts * 3) ? xyz[gi] : 0.0f;
    }
    const float scale = scales[l];
    const int   off_l = level_offsets[l];
    const float lox = bounds[0], loy = bounds[1], loz = bounds[2];
    const float hix = bounds[3] - 1e-6f;
    const float hiy = bounds[4] - 1e-6f;
    const float hiz = bounds[5] - 1e-6f;
    const float size = fmaxf(fmaxf(bounds[3] - bounds[0], bounds[4] - bounds[1]),
                             bounds[5] - bounds[2]);
    const float inv_size = 1.0f / size;
    __syncthreads();

    const int n = block_base + p;
    const bool active = (n < npts);
    const float rx = sxyz[p * 3 + 0];
    const float ry = sxyz[p * 3 + 1];
    const float rz = sxyz[p * 3 + 2];
    float acc0 = 0.f, acc1 = 0.f, acc2 = 0.f, acc3 = 0.f, acc4 = 0.f, acc5 = 0.f;

    if (active) {
        const float x = fminf(fmaxf(rx, lox), hix);
        const float y = fminf(fmaxf(ry, loy), hiy);
        const float z = fminf(fmaxf(rz, loz), hiz);
        const float xn = (x - lox) * inv_size;
        const float yn = (y - loy) * inv_size;
        const float zn = (z - loz) * inv_size;
        const int r1 = (int)scale + 1;
        const int r1sq = r1 * r1;
        const float fx = xn * scale, fy = yn * scale, fz = zn * scale;
        const float bxf = floorf(fx), byf = floorf(fy), bzf = floorf(fz);
        const float ox = fx - bxf, oy = fy - byf, oz = fz - bzf;
        const int i000 = (int)bxf * r1sq + (int)byf * r1 + (int)bzf + off_l;
        const float* p0 = data + 3 * (size_t)i000;
        const float* p1 = p0 + 3 * r1;
        const float* p2 = p0 + 3 * r1sq;
        const float* p3 = p2 + 3 * r1;
        const f4u a0 = *(const f4u*)p0;  const f2u b0 = *(const f2u*)(p0 + 4);
        const f4u a1 = *(const f4u*)p1;  const f2u b1 = *(const f2u*)(p1 + 4);
        const f4u a2 = *(const f4u*)p2;  const f2u b2 = *(const f2u*)(p2 + 4);
        const f4u a3 = *(const f4u*)p3;  const f2u b3 = *(const f2u*)(p3 + 4);
        const float freq = (float)(1 << l);
        const float wz0 = 1.0f - oz;
        const float wx1 = ox, wx0 = 1.0f - ox;
        const float wy1 = oy, wy0 = 1.0f - oy;
        float sn, cs;
        #define PAIR(a, b, WXY)                                                   \
        {                                                                         \
            const float w0 = (WXY) * wz0;                                         \
            const float w1 = (WXY) * oz;                                          \
            __sincosf(a.x * freq, &sn, &cs); acc0 += w0 * sn; acc3 += w0 * cs;    \
            __sincosf(a.y * freq, &sn, &cs); acc1 += w0 * sn; acc4 += w0 * cs;    \
            __sincosf(a.z * freq, &sn, &cs); acc2 += w0 * sn; acc5 += w0 * cs;    \
            __sincosf(a.w * freq, &sn, &cs); acc0 += w1 * sn; acc3 += w1 * cs;    \
            __sincosf(b.x * freq, &sn, &cs); acc1 += w1 * sn; acc4 += w1 * cs;    \
            __sincosf(b.y * freq, &sn, &cs); acc2 += w1 * sn; acc5 += w1 * cs;    \
        }
        PAIR(a0, b0, wx0 * wy0)
        PAIR(a1, b1, wx0 * wy1)
        PAIR(a2, b2, wx1 * wy0)
        PAIR(a3, b3, wx1 * wy1)
        #undef PAIR
    }
    {
        float* row = sres[p];
        const int c = 3 + l * 6;
        row[c + 0] = acc0; row[c + 1] = acc1; row[c + 2] = acc2;
        row[c + 3] = acc3; row[c + 4] = acc4; row[c + 5] = acc5;
        if (l == 0) { row[0] = rx; row[1] = ry; row[2] = rz; }
    }
    __syncthreads();
    {
        const float* flat = &sres[0][0];
        float* ob = out + (size_t)block_base * ROW_F;
        const int lim = npts * ROW_F - block_base * ROW_F;
        for (int i = tid; i < PTS_PER_BLOCK * ROW_F; i += 256)
            if (i < lim) ob[i] = flat[i];
    }
}

extern "C" void kernel_launch(void* const* d_in, const int* in_sizes, int n_in,
                              void* d_out, int out_size, void* d_ws, size_t ws_size,
                              hipStream_t stream) {
    const float* xyz           = (const float*)d_in[0];
    const float* data          = (const float*)d_in[1];
    const float* scales        = (const float*)d_in[2];
    const int*   level_offsets = (const int*)d_in[3];
    const float* bounds        = (const float*)d_in[4];
    float* out = (float*)d_out;

    const int npts = in_sizes[0] / 3;
    const int T    = in_sizes[1] / 3;
    const int nblocks = (npts + PTS_PER_BLOCK - 1) / PTS_PER_BLOCK;

    const size_t ws_needed = (size_t)T * sizeof(uint4);
    if (d_ws != nullptr && ws_size >= ws_needed) {
        uint4* tab = (uint4*)d_ws;
        phase_repack<<<(T + 255) / 256, 256, 0, stream>>>(data, level_offsets, tab, T);
        dagrid_kernel<<<nblocks, 256, 0, stream>>>(xyz, tab, scales, level_offsets,
                                                   bounds, out, npts);
    } else {
        dagrid_kernel_direct<<<nblocks, 256, 0, stream>>>(xyz, data, scales,
                                                          level_offsets, bounds,
                                                          out, npts);
    }
}

// Round 6
// 129.240 us; speedup vs baseline: 1.1845x; 1.1845x over previous
//
#include <hip/hip_runtime.h>

#define NLEV 8
#define PTS_PER_BLOCK 64
#define ROW_F 51   // 3 + 6*NLEV

// 16B load at 8B-aligned address (two consecutive 8B table entries)
typedef unsigned int u4a8 __attribute__((ext_vector_type(4), aligned(8)));

// ---------------------------------------------------------------------------
// Phase repack: data (T anchors x 3 f32) -> tab (T x 8B entries).
// Entry i = anchor i's 3 components as u16 phases (revolutions*65536),
// phase = fract(val * 2^l / 2pi), l = level owning anchor i. High halves of
// the padded u16 slots are zero by construction.
// ---------------------------------------------------------------------------
__global__ __launch_bounds__(256) void phase_repack8(
    const float* __restrict__ data,
    const int*   __restrict__ level_offsets,
    uint2* __restrict__ tab, int T)
{
    __shared__ float sv[256 * 3];
    __shared__ int   soff[NLEV];
    const int tid  = threadIdx.x;
    const int base = blockIdx.x * 256;

    if (tid < NLEV) soff[tid] = level_offsets[tid];
    for (int k = tid; k < 256 * 3; k += 256) {
        const int gi = base * 3 + k;
        sv[k] = (gi < T * 3) ? data[gi] : 0.0f;   // coalesced stream
    }
    __syncthreads();

    const int i = base + tid;
    if (i >= T) return;

    int l = 0;
    #pragma unroll
    for (int j = 1; j < NLEV; ++j) l += (i >= soff[j]) ? 1 : 0;
    const float s = (float)(1 << l) * 0.15915494309189535f;   // freq / 2pi

    unsigned q[3];
    #pragma unroll
    for (int k = 0; k < 3; ++k) {
        float f = sv[tid * 3 + k] * s;
        f -= floorf(f);                             // [0,1) revolutions
        q[k] = ((unsigned)(f * 65536.0f + 0.5f)) & 0xffffu;  // 65536 wraps to 0
    }
    tab[i] = make_uint2(q[0] | (q[1] << 16), q[2]);
}

// sin/cos on revolutions in [0,1): pre-reduced domain for HW trans units
__device__ __forceinline__ void sincos_rev(float r, float& sn, float& cs) {
    asm("v_sin_f32 %0, %1" : "=v"(sn) : "v"(r));
    asm("v_cos_f32 %0, %1" : "=v"(cs) : "v"(r));
}

// ---------------------------------------------------------------------------
// Main kernel: 2 (point,level) units per thread, 4 aligned dwordx4 per unit.
// ---------------------------------------------------------------------------
__global__ __launch_bounds__(256) void dagrid_kernel(
    const float* __restrict__ xyz,
    const uint2* __restrict__ tab,
    const float* __restrict__ scales,
    const int*   __restrict__ level_offsets,
    const float* __restrict__ bounds,
    float* __restrict__ out,
    int npts)
{
    __shared__ alignas(16) float sxyz[PTS_PER_BLOCK * 3];
    __shared__ alignas(16) float sres[PTS_PER_BLOCK][ROW_F];

    const int tid = threadIdx.x;
    const int l   = tid & 7;        // level (shared by both units)
    const int p   = tid >> 3;       // local point A: 0..31; point B: p+32
    const int block_base = blockIdx.x * PTS_PER_BLOCK;
    const bool full_block = (block_base + PTS_PER_BLOCK <= npts);

    if (full_block) {
        if (tid < 48)
            ((float4*)sxyz)[tid] = ((const float4*)(xyz + (size_t)block_base * 3))[tid];
    } else if (tid < PTS_PER_BLOCK * 3) {
        const int gi = block_base * 3 + tid;
        sxyz[tid] = (gi < npts * 3) ? xyz[gi] : 0.0f;
    }

    const float scale = scales[l];
    const int   off_l = level_offsets[l];

    const float lox = bounds[0], loy = bounds[1], loz = bounds[2];
    const float hix = bounds[3] - 1e-6f;
    const float hiy = bounds[4] - 1e-6f;
    const float hiz = bounds[5] - 1e-6f;
    const float size = fmaxf(fmaxf(bounds[3] - bounds[0], bounds[4] - bounds[1]),
                             bounds[5] - bounds[2]);
    const float inv_size = 1.0f / size;

    __syncthreads();

    const int nA = block_base + p;
    const int nB = nA + 32;
    const bool actA = (nA < npts);
    const bool actB = (nB < npts);

    const float rxA = sxyz[p * 3 + 0], ryA = sxyz[p * 3 + 1], rzA = sxyz[p * 3 + 2];
    const float rxB = sxyz[(p + 32) * 3 + 0], ryB = sxyz[(p + 32) * 3 + 1],
                rzB = sxyz[(p + 32) * 3 + 2];

    const int r1   = (int)scale + 1;
    const int r1sq = r1 * r1;

    // ---- address computation for both units
    #define ADDR(rx, ry, rz, act, ox, oy, oz, idx)                                \
    {                                                                             \
        const float x = fminf(fmaxf(rx, lox), hix);                               \
        const float y = fminf(fmaxf(ry, loy), hiy);                               \
        const float z = fminf(fmaxf(rz, loz), hiz);                               \
        const float fx = (x - lox) * inv_size * scale;                            \
        const float fy = (y - loy) * inv_size * scale;                            \
        const float fz = (z - loz) * inv_size * scale;                            \
        const float bxf = floorf(fx), byf = floorf(fy), bzf = floorf(fz);         \
        ox = fx - bxf; oy = fy - byf; oz = fz - bzf;                              \
        idx = act ? ((int)bxf * r1sq + (int)byf * r1 + (int)bzf + off_l) : 0;     \
    }
    float oxA, oyA, ozA, oxB, oyB, ozB;
    int idxA, idxB;
    ADDR(rxA, ryA, rzA, actA, oxA, oyA, ozA, idxA)
    ADDR(rxB, ryB, rzB, actB, oxB, oyB, ozB, idxB)
    #undef ADDR

    // ---- gather: 8 x dwordx4 in flight (2 units x 4 corner-pairs)
    const u4a8 eA0 = *(const u4a8*)(tab + idxA);
    const u4a8 eA1 = *(const u4a8*)(tab + idxA + r1);
    const u4a8 eA2 = *(const u4a8*)(tab + idxA + r1sq);
    const u4a8 eA3 = *(const u4a8*)(tab + idxA + r1sq + r1);
    const u4a8 eB0 = *(const u4a8*)(tab + idxB);
    const u4a8 eB1 = *(const u4a8*)(tab + idxB + r1);
    const u4a8 eB2 = *(const u4a8*)(tab + idxB + r1sq);
    const u4a8 eB3 = *(const u4a8*)(tab + idxB + r1sq + r1);

    const float K = 1.0f / 65536.0f;   // u16 phase -> revolutions

    // e = [p0x|p0y<<16, p0z, p1x|p1y<<16, p1z] (high halves of .y/.w are zero)
    #define PAIRE(e, WXY, oz_, wz0_, a0, a1, a2, a3, a4, a5)                      \
    {                                                                             \
        const float w0 = (WXY) * (wz0_);                                          \
        const float w1 = (WXY) * (oz_);                                           \
        float sn, cs;                                                             \
        sincos_rev((float)(e.x & 0xffffu) * K, sn, cs); a0 += w0*sn; a3 += w0*cs; \
        sincos_rev((float)(e.x >> 16)     * K, sn, cs); a1 += w0*sn; a4 += w0*cs; \
        sincos_rev((float)(e.y)           * K, sn, cs); a2 += w0*sn; a5 += w0*cs; \
        sincos_rev((float)(e.z & 0xffffu) * K, sn, cs); a0 += w1*sn; a3 += w1*cs; \
        sincos_rev((float)(e.z >> 16)     * K, sn, cs); a1 += w1*sn; a4 += w1*cs; \
        sincos_rev((float)(e.w)           * K, sn, cs); a2 += w1*sn; a5 += w1*cs; \
    }

    float a0 = 0.f, a1 = 0.f, a2 = 0.f, a3 = 0.f, a4 = 0.f, a5 = 0.f;
    {
        const float wz0 = 1.0f - ozA;
        const float wx0 = 1.0f - oxA, wy0 = 1.0f - oyA;
        PAIRE(eA0, wx0 * wy0, ozA, wz0, a0, a1, a2, a3, a4, a5)
        PAIRE(eA1, wx0 * oyA, ozA, wz0, a0, a1, a2, a3, a4, a5)
        PAIRE(eA2, oxA * wy0, ozA, wz0, a0, a1, a2, a3, a4, a5)
        PAIRE(eA3, oxA * oyA, ozA, wz0, a0, a1, a2, a3, a4, a5)
    }
    float b0 = 0.f, b1 = 0.f, b2 = 0.f, b3 = 0.f, b4 = 0.f, b5 = 0.f;
    {
        const float wz0 = 1.0f - ozB;
        const float wx0 = 1.0f - oxB, wy0 = 1.0f - oyB;
        PAIRE(eB0, wx0 * wy0, ozB, wz0, b0, b1, b2, b3, b4, b5)
        PAIRE(eB1, wx0 * oyB, ozB, wz0, b0, b1, b2, b3, b4, b5)
        PAIRE(eB2, oxB * wy0, ozB, wz0, b0, b1, b2, b3, b4, b5)
        PAIRE(eB3, oxB * oyB, ozB, wz0, b0, b1, b2, b3, b4, b5)
    }
    #undef PAIRE

    {
        const int c = 3 + l * 6;
        float* rowA = sres[p];
        rowA[c + 0] = a0; rowA[c + 1] = a1; rowA[c + 2] = a2;
        rowA[c + 3] = a3; rowA[c + 4] = a4; rowA[c + 5] = a5;
        float* rowB = sres[p + 32];
        rowB[c + 0] = b0; rowB[c + 1] = b1; rowB[c + 2] = b2;
        rowB[c + 3] = b3; rowB[c + 4] = b4; rowB[c + 5] = b5;
        if (l == 0) {
            rowA[0] = rxA; rowA[1] = ryA; rowA[2] = rzA;
            rowB[0] = rxB; rowB[1] = ryB; rowB[2] = rzB;
        }
    }
    __syncthreads();

    // coalesced write: 64*51 = 3264 floats = 816 float4 per block (16B aligned)
    if (full_block) {
        const float4* flat4 = (const float4*)&sres[0][0];
        float4* ob4 = (float4*)(out + (size_t)block_base * ROW_F);
        for (int i = tid; i < (PTS_PER_BLOCK * ROW_F) / 4; i += 256)
            ob4[i] = flat4[i];
    } else {
        const float* flat = &sres[0][0];
        float* ob = out + (size_t)block_base * ROW_F;
        const int lim = npts * ROW_F - block_base * ROW_F;
        for (int i = tid; i < PTS_PER_BLOCK * ROW_F; i += 256)
            if (i < lim) ob[i] = flat[i];
    }
}

// ---------------------------------------------------------------------------
// Fallback (ws too small): direct fp32 gather (x4u + x2u), known-good (R3).
// ---------------------------------------------------------------------------
typedef float f4u __attribute__((ext_vector_type(4), aligned(4)));
typedef float f2u __attribute__((ext_vector_type(2), aligned(4)));

__global__ __launch_bounds__(256) void dagrid_kernel_direct(
    const float* __restrict__ xyz,
    const float* __restrict__ data,
    const float* __restrict__ scales,
    const int*   __restrict__ level_offsets,
    const float* __restrict__ bounds,
    float* __restrict__ out,
    int npts)
{
    __shared__ alignas(16) float sxyz[32 * 3];
    __shared__ alignas(16) float sres[32][ROW_F];

    const int tid = threadIdx.x;
    const int l   = tid & 7;
    const int p   = tid >> 3;
    const int block_base = blockIdx.x * 32;

    if (tid < 32 * 3) {
        const int gi = block_base * 3 + tid;
        sxyz[tid] = (gi < npts * 3) ? xyz[gi] : 0.0f;
    }
    const float scale = scales[l];
    const int   off_l = level_offsets[l];
    const float lox = bounds[0], loy = bounds[1], loz = bounds[2];
    const float hix = bounds[3] - 1e-6f;
    const float hiy = bounds[4] - 1e-6f;
    const float hiz = bounds[5] - 1e-6f;
    const float size = fmaxf(fmaxf(bounds[3] - bounds[0], bounds[4] - bounds[1]),
                             bounds[5] - bounds[2]);
    const float inv_size = 1.0f / size;
    __syncthreads();

    const int n = block_base + p;
    const bool active = (n < npts);
    const float rx = sxyz[p * 3 + 0];
    const float ry = sxyz[p * 3 + 1];
    const float rz = sxyz[p * 3 + 2];
    float acc0 = 0.f, acc1 = 0.f, acc2 = 0.f, acc3 = 0.f, acc4 = 0.f, acc5 = 0.f;

    if (active) {
        const float x = fminf(fmaxf(rx, lox), hix);
        const float y = fminf(fmaxf(ry, loy), hiy);
        const float z = fminf(fmaxf(rz, loz), hiz);
        const float xn = (x - lox) * inv_size;
        const float yn = (y - loy) * inv_size;
        const float zn = (z - loz) * inv_size;
        const int r1 = (int)scale + 1;
        const int r1sq = r1 * r1;
        const float fx = xn * scale, fy = yn * scale, fz = zn * scale;
        const float bxf = floorf(fx), byf = floorf(fy), bzf = floorf(fz);
        const float ox = fx - bxf, oy = fy - byf, oz = fz - bzf;
        const int i000 = (int)bxf * r1sq + (int)byf * r1 + (int)bzf + off_l;
        const float* p0 = data + 3 * (size_t)i000;
        const float* p1 = p0 + 3 * r1;
        const float* p2 = p0 + 3 * r1sq;
        const float* p3 = p2 + 3 * r1;
        const f4u q0 = *(const f4u*)p0;  const f2u g0 = *(const f2u*)(p0 + 4);
        const f4u q1 = *(const f4u*)p1;  const f2u g1 = *(const f2u*)(p1 + 4);
        const f4u q2 = *(const f4u*)p2;  const f2u g2 = *(const f2u*)(p2 + 4);
        const f4u q3 = *(const f4u*)p3;  const f2u g3 = *(const f2u*)(p3 + 4);
        const float freq = (float)(1 << l);
        const float wz0 = 1.0f - oz;
        const float wx1 = ox, wx0 = 1.0f - ox;
        const float wy1 = oy, wy0 = 1.0f - oy;
        float sn, cs;
        #define PAIR(a, b, WXY)                                                   \
        {                                                                         \
            const float w0 = (WXY) * wz0;                                         \
            const float w1 = (WXY) * oz;                                          \
            __sincosf(a.x * freq, &sn, &cs); acc0 += w0 * sn; acc3 += w0 * cs;    \
            __sincosf(a.y * freq, &sn, &cs); acc1 += w0 * sn; acc4 += w0 * cs;    \
            __sincosf(a.z * freq, &sn, &cs); acc2 += w0 * sn; acc5 += w0 * cs;    \
            __sincosf(a.w * freq, &sn, &cs); acc0 += w1 * sn; acc3 += w1 * cs;    \
            __sincosf(b.x * freq, &sn, &cs); acc1 += w1 * sn; acc4 += w1 * cs;    \
            __sincosf(b.y * freq, &sn, &cs); acc2 += w1 * sn; acc5 += w1 * cs;    \
        }
        PAIR(q0, g0, wx0 * wy0)
        PAIR(q1, g1, wx0 * wy1)
        PAIR(q2, g2, wx1 * wy0)
        PAIR(q3, g3, wx1 * wy1)
        #undef PAIR
    }
    {
        float* row = sres[p];
        const int c = 3 + l * 6;
        row[c + 0] = acc0; row[c + 1] = acc1; row[c + 2] = acc2;
        row[c + 3] = acc3; row[c + 4] = acc4; row[c + 5] = acc5;
        if (l == 0) { row[0] = rx; row[1] = ry; row[2] = rz; }
    }
    __syncthreads();
    {
        const float* flat = &sres[0][0];
        float* ob = out + (size_t)block_base * ROW_F;
        const int lim = npts * ROW_F - block_base * ROW_F;
        for (int i = tid; i < 32 * ROW_F; i += 256)
            if (i < lim) ob[i] = flat[i];
    }
}

extern "C" void kernel_launch(void* const* d_in, const int* in_sizes, int n_in,
                              void* d_out, int out_size, void* d_ws, size_t ws_size,
                              hipStream_t stream) {
    const float* xyz           = (const float*)d_in[0];
    const float* data          = (const float*)d_in[1];
    const float* scales        = (const float*)d_in[2];
    const int*   level_offsets = (const int*)d_in[3];
    const float* bounds        = (const float*)d_in[4];
    float* out = (float*)d_out;

    const int npts = in_sizes[0] / 3;
    const int T    = in_sizes[1] / 3;

    const size_t ws_needed = (size_t)T * sizeof(uint2);
    if (d_ws != nullptr && ws_size >= ws_needed) {
        uint2* tab = (uint2*)d_ws;
        phase_repack8<<<(T + 255) / 256, 256, 0, stream>>>(data, level_offsets, tab, T);
        const int nblocks = (npts + PTS_PER_BLOCK - 1) / PTS_PER_BLOCK;
        dagrid_kernel<<<nblocks, 256, 0, stream>>>(xyz, tab, scales, level_offsets,
                                                   bounds, out, npts);
    } else {
        const int nblocks = (npts + 31) / 32;
        dagrid_kernel_direct<<<nblocks, 256, 0, stream>>>(xyz, data, scales,
                                                          level_offsets, bounds,
                                                          out, npts);
    }
}